// Round 5
// baseline (165.820 us; speedup 1.0000x reference)
//
#include <hip/hip_runtime.h>

#define NN 50000
#define NPAD 50048           // featb rows (tail zeroed); NPAD-1 is the shared zero-row
#define NE 500000
#define DD 128
#define NT16 3125            // ceil(NN/16) 16-node tiles
#define ZROW (NPAD - 1)

// ALPHA = 0.5 → both sqrt(ALPHA) and sqrt(1-ALPHA) are sqrt(0.5).
__device__ __constant__ float SQ_A = 0.70710678118654752440f;

typedef __attribute__((ext_vector_type(8))) short short8;
typedef __attribute__((ext_vector_type(4))) float float4v;

// float → bf16 bits, round-to-nearest-even.
__device__ inline ushort f2bf(float f)
{
    uint u = __float_as_uint(f);
    u += 0x7fffu + ((u >> 16) & 1u);
    return (ushort)(u >> 16);
}
__device__ inline uint pk2(float a, float b)
{
    return (uint)f2bf(a) | ((uint)f2bf(b) << 16);
}
__device__ inline float bf_lo(uint d) { return __uint_as_float(d << 16); }
__device__ inline float bf_hi(uint d) { return __uint_as_float(d & 0xffff0000u); }

// ---------------------------------------------------------------------------
// Mega-prep: (a) edge placement into fixed-capacity per-(node,rel) buckets
// payload[n*64 + r*32 + idx] = src (ushort; Poisson(5)/bucket → P(>32)≈1e-11);
// (b) feat fp32 → featb bf16 [NPAD][128] (rows >= NN zeroed → ZROW is the
// dummy row for padded gather slots); (c) W/loop_w → wtb bf16, ×sqrt(.5),
// row-permuted for the packed epilogue. cnt[2*NPAD] pre-zeroed by memset.
// ---------------------------------------------------------------------------
#define MP_FEAT (NPAD * 16)          // 16 chunks of 8 elems per row
#define MP_WTB  (3 * 2048)
#define MP_TASKS (NE + MP_FEAT + MP_WTB)

__global__ __launch_bounds__(256)
void mega_prep_kernel(const float* __restrict__ feat,
                      const float* __restrict__ weight,
                      const float* __restrict__ loop_w,
                      const int* __restrict__ src,
                      const int* __restrict__ dst,
                      const int* __restrict__ ety,
                      ushort* __restrict__ featb,
                      ushort* __restrict__ wtb,
                      int* __restrict__ cnt,
                      ushort* __restrict__ payload)
{
    int t = blockIdx.x * 256 + threadIdx.x;
    if (t < NE) {
        // ---- edge placement (latency-heavy: schedule first) ----
        int d = dst[t], r = ety[t], s = src[t];
        int idx = atomicAdd(&cnt[2 * d + r], 1);
        if (idx < 32) payload[(d << 6) + (r << 5) + idx] = (ushort)s;
    } else if (t < NE + MP_FEAT) {
        int u   = t - NE;
        int row = u >> 4;
        int c   = u & 15;            // k-chunk: elems c*8 .. c*8+7
        float4 v0 = make_float4(0.f, 0.f, 0.f, 0.f), v1 = v0;
        if (row < NN) {
            const float4* p = (const float4*)(feat + (size_t)row * DD + c * 8);
            v0 = p[0]; v1 = p[1];
        }
        uint4 pk;
        pk.x = pk2(v0.x, v0.y); pk.y = pk2(v0.z, v0.w);
        pk.z = pk2(v1.x, v1.y); pk.w = pk2(v1.z, v1.w);
        *(uint4*)&featb[(size_t)row * DD + c * 8] = pk;
    } else if (t < MP_TASKS) {
        int u   = t - (NE + MP_FEAT);
        int seg = u >> 11;           // 0,1 → relations; 2 → loop
        int c   = (u >> 7) & 15;     // k-chunk
        int col = u & 127;           // actual output column
        const float* wsrc = (seg < 2) ? (weight + (size_t)seg * DD * DD)
                                      : loop_w;
        float v[8];
#pragma unroll
        for (int j = 0; j < 8; ++j)
            v[j] = wsrc[(size_t)(c * 8 + j) * DD + col] * SQ_A;
        uint4 pk;
        pk.x = pk2(v[0], v[1]); pk.y = pk2(v[2], v[3]);
        pk.z = pk2(v[4], v[5]); pk.w = pk2(v[6], v[7]);
        int prow = (col >> 5) * 32 + ((col & 1) << 4) + ((col & 31) >> 1);
        *(uint4*)&wtb[((size_t)seg * DD + prow) * DD + c * 8] = pk;
    }
}

// ---------------------------------------------------------------------------
// Overflow batch (deg_rel > 8; P ≈ 7% per bucket — off the hot path).
// ---------------------------------------------------------------------------
__device__ inline void ov8(const uint* __restrict__ fbu,
                           const ushort* __restrict__ pb,
                           int e, int c, int lane,
                           float2& sa, float2& sb)
{
    uint4 ch = *(const uint4*)(pb + e);
    uint w[4] = {ch.x, ch.y, ch.z, ch.w};
    uint d[8];
#pragma unroll
    for (int j = 0; j < 8; ++j) {
        int ps = __builtin_amdgcn_readfirstlane(
            (int)((w[j >> 1] >> ((j & 1) << 4)) & 0xffffu));
        ps = (e + j < c) ? ps : ZROW;
        d[j] = fbu[((size_t)ps << 6) + lane];
    }
#pragma unroll
    for (int j = 0; j < 8; j += 2) {
        sa.x += bf_lo(d[j]);     sa.y += bf_hi(d[j]);
        sb.x += bf_lo(d[j + 1]); sb.y += bf_hi(d[j + 1]);
    }
}

// ---------------------------------------------------------------------------
// Fused aggregate + transform. One block per 16-NODE tile, 4 waves; wave wv
// gathers nodes [wv*4, wv*4+4) — serial chain halved vs the 32-node tile,
// grid doubled to 3125 blocks; LDS 13 KB + VGPR≈40 → 8 blocks/CU (32
// waves/CU target) so many more gather batches are in flight per CU.
// Gather layout (R1-proven): lane owns cols [2*lane, 2*lane+2); 17 loads
// per node (16 edge slots + self) issued back-to-back; slot padding via
// ZROW (all-zero row) — no tail, no divergence; next node's cnt + payload
// chunks prefetched one iteration ahead.
// ---------------------------------------------------------------------------
__global__ __launch_bounds__(256, 8)
void fused_agg_mfma_kernel(const ushort* __restrict__ featb,
                           const ushort* __restrict__ wtb,
                           const float* __restrict__ h_bias,
                           const int* __restrict__ cnt,
                           const ushort* __restrict__ payload,
                           float* __restrict__ out)
{
    __shared__ ushort sAgg[3][16][136];   // 13056 B → 8+ blocks/CU

    const int node0 = blockIdx.x * 16;
    const int wv    = threadIdx.x >> 6;
    const int lane  = threadIdx.x & 63;
    const int mq    = lane & 15;
    const int quad  = lane >> 4;
    const int col0  = wv * 32;
    const uint* fbu = (const uint*)featb;

    // --- Phase 1: pipelined gather-aggregate, 4 nodes per wave. ---
    int  nnC = __builtin_amdgcn_readfirstlane(node0 + wv * 4);
    int2 ccC = *(const int2*)&cnt[2 * nnC];
    uint4 chA = *(const uint4*)(payload + ((size_t)nnC << 6));
    uint4 chB = *(const uint4*)(payload + ((size_t)nnC << 6) + 32);

#pragma unroll 1
    for (int i = 0; i < 4; ++i) {
        const int nl = wv * 4 + i;
        // self row (independent load, issued first)
        uint selfd = fbu[((size_t)nnC << 6) + lane];
        const int c0 = ccC.x < 32 ? ccC.x : 32;
        const int c1 = ccC.y < 32 ? ccC.y : 32;
        const uint wA[4] = {chA.x, chA.y, chA.z, chA.w};
        const uint wB[4] = {chB.x, chB.y, chB.z, chB.w};
        uint d[16];
#pragma unroll
        for (int j = 0; j < 8; ++j) {
            int ps = __builtin_amdgcn_readfirstlane(
                (int)((wA[j >> 1] >> ((j & 1) << 4)) & 0xffffu));
            ps = (j < c0) ? ps : ZROW;
            d[j] = fbu[((size_t)ps << 6) + lane];
        }
#pragma unroll
        for (int j = 0; j < 8; ++j) {
            int ps = __builtin_amdgcn_readfirstlane(
                (int)((wB[j >> 1] >> ((j & 1) << 4)) & 0xffffu));
            ps = (j < c1) ? ps : ZROW;
            d[8 + j] = fbu[((size_t)ps << 6) + lane];
        }
        // prefetch next node's metadata (in-bounds even at i==3: node0+16
        // ≤ 50000 < NPAD; cnt rows ≥ NN are zeroed → c==0 → unused)
        const int nnN = __builtin_amdgcn_readfirstlane(node0 + wv * 4 + i + 1);
        int2  ccN = *(const int2*)&cnt[2 * nnN];
        uint4 chAN = *(const uint4*)(payload + ((size_t)nnN << 6));
        uint4 chBN = *(const uint4*)(payload + ((size_t)nnN << 6) + 32);
        // accumulate current node (4 independent chains)
        float2 s0a = make_float2(0.f, 0.f), s0b = s0a, s1a = s0a, s1b = s0a;
#pragma unroll
        for (int j = 0; j < 8; j += 2) {
            s0a.x += bf_lo(d[j]);         s0a.y += bf_hi(d[j]);
            s0b.x += bf_lo(d[j + 1]);     s0b.y += bf_hi(d[j + 1]);
            s1a.x += bf_lo(d[8 + j]);     s1a.y += bf_hi(d[8 + j]);
            s1b.x += bf_lo(d[8 + j + 1]); s1b.y += bf_hi(d[8 + j + 1]);
        }
        if (c0 > 8)
            for (int e = 8; e < c0; e += 8)
                ov8(fbu, payload + ((size_t)nnC << 6), e, c0, lane, s0a, s0b);
        if (c1 > 8)
            for (int e = 8; e < c1; e += 8)
                ov8(fbu, payload + ((size_t)nnC << 6) + 32, e, c1, lane, s1a, s1b);
        *(uint*)&sAgg[0][nl][2 * lane] = pk2(s0a.x + s0b.x, s0a.y + s0b.y);
        *(uint*)&sAgg[1][nl][2 * lane] = pk2(s1a.x + s1b.x, s1a.y + s1b.y);
        *(uint*)&sAgg[2][nl][2 * lane] = selfd;
        nnC = nnN; ccC = ccN; chA = chAN; chB = chBN;
    }
    __syncthreads();

    // --- Phase 2: MFMA, 3 uniform panels, shared accumulator (M=16). ---
    float4v acc[2];
    acc[0] = (float4v){0.f, 0.f, 0.f, 0.f};
    acc[1] = (float4v){0.f, 0.f, 0.f, 0.f};

#pragma unroll 1
    for (int r = 0; r < 3; ++r) {
        const ushort* wseg = wtb + (size_t)r * DD * DD;
        short8 bfrag[2][4];
#pragma unroll
        for (int nt = 0; nt < 2; ++nt)
#pragma unroll
            for (int ks = 0; ks < 4; ++ks)
                bfrag[nt][ks] = *(const short8*)
                    &wseg[(size_t)(col0 + nt * 16 + mq) * DD + ks * 32 + quad * 8];
#pragma unroll
        for (int ks = 0; ks < 4; ++ks) {
            short8 a = *(const short8*)&sAgg[r][mq][ks * 32 + quad * 8];
#pragma unroll
            for (int nt = 0; nt < 2; ++nt)
                acc[nt] = __builtin_amdgcn_mfma_f32_16x16x32_bf16(
                    a, bfrag[nt][ks], acc[nt], 0, 0, 0);
        }
    }

    // Epilogue. D row = quad*4 + rr; lane mq owns cols col0+2mq, +1
    // (wtb row permutation makes nt=0/1 frags the even/odd columns).
    float2 bv = *(const float2*)&h_bias[col0 + 2 * mq];
#pragma unroll
    for (int rr = 0; rr < 4; ++rr) {
        int node = node0 + quad * 4 + rr;
        if (node < NN) {
            float2 v = make_float2(acc[0][rr] + bv.x,
                                   acc[1][rr] + bv.y);
            *(float2*)&out[(size_t)node * DD + col0 + 2 * mq] = v;
        }
    }
}

// ---------------------------------------------------------------------------
// Fallback (small ws): fp32 out-init + fused per-edge matvec.
// ---------------------------------------------------------------------------
__global__ __launch_bounds__(256)
void loop_init_kernel(const float* __restrict__ feat,
                      const float* __restrict__ loop_weight,
                      const float* __restrict__ h_bias,
                      float* __restrict__ out)
{
    const int n = blockIdx.x * 4 + (threadIdx.x >> 6);
    if (n >= NN) return;
    const int lane = threadIdx.x & 63;
    const float2 fv = ((const float2*)(feat + (size_t)n * DD))[lane];
    float a0 = h_bias[lane], a1 = h_bias[lane + 64];
    for (int k = 0; k < 64; ++k) {
        float f0 = __shfl(fv.x, k, 64);
        float f1 = __shfl(fv.y, k, 64);
        a0 += SQ_A * (f0 * loop_weight[(size_t)(2 * k) * DD + lane]
                    + f1 * loop_weight[(size_t)(2 * k + 1) * DD + lane]);
        a1 += SQ_A * (f0 * loop_weight[(size_t)(2 * k) * DD + lane + 64]
                    + f1 * loop_weight[(size_t)(2 * k + 1) * DD + lane + 64]);
    }
    out[(size_t)n * DD + lane] = a0;
    out[(size_t)n * DD + lane + 64] = a1;
}

__global__ __launch_bounds__(256)
void fused_edge_kernel(const float* __restrict__ feat,
                       const int* __restrict__ src, const int* __restrict__ dst,
                       const int* __restrict__ ety,
                       const float* __restrict__ weight,
                       float* __restrict__ out)
{
    const int wave  = threadIdx.x >> 6;
    const int lane  = threadIdx.x & 63;
    const int nwav  = gridDim.x * 4;
    for (int e = blockIdx.x * 4 + wave; e < NE; e += nwav) {
        const int s = src[e];
        const int d = dst[e];
        const int r = ety[e];
        const float2 fv = ((const float2*)(feat + (size_t)s * DD))[lane];
        const float* W = weight + (size_t)r * DD * DD;
        float a0 = 0.f, a1 = 0.f;
        for (int k = 0; k < 64; ++k) {
            float f0 = __shfl(fv.x, k, 64);
            float f1 = __shfl(fv.y, k, 64);
            a0 += f0 * W[(size_t)(2 * k) * DD + lane]
                + f1 * W[(size_t)(2 * k + 1) * DD + lane];
            a1 += f0 * W[(size_t)(2 * k) * DD + lane + 64]
                + f1 * W[(size_t)(2 * k + 1) * DD + lane + 64];
        }
        atomicAdd(out + (size_t)d * DD + lane,      SQ_A * a0);
        atomicAdd(out + (size_t)d * DD + lane + 64, SQ_A * a1);
    }
}

extern "C" void kernel_launch(void* const* d_in, const int* in_sizes, int n_in,
                              void* d_out, int out_size, void* d_ws, size_t ws_size,
                              hipStream_t stream)
{
    const float* feat   = (const float*)d_in[0];
    const int*   src    = (const int*)d_in[1];
    const int*   dst    = (const int*)d_in[2];
    const int*   ety    = (const int*)d_in[3];
    const float* weight = (const float*)d_in[4];
    const float* loop_w = (const float*)d_in[5];
    const float* h_bias = (const float*)d_in[6];
    float* out  = (float*)d_out;

    // Workspace layout (all sections 16B-multiple sized). ~19.7 MiB total.
    char* p = (char*)d_ws;
    ushort* featb   = (ushort*)p; p += (size_t)NPAD * DD * 2;       // 12.81 MB
    ushort* wtb     = (ushort*)p; p += (size_t)3 * DD * DD * 2;     // 96 KB
    int*    cnt     = (int*)p;    p += (size_t)2 * NPAD * 4;        // 400 KB
    ushort* payload = (ushort*)p; p += (size_t)NPAD * 64 * 2;       // 6.4 MB
    const size_t need_full = (size_t)(p - (char*)d_ws);

    if (ws_size >= need_full) {
        hipMemsetAsync(cnt, 0, (size_t)2 * NPAD * 4, stream);
        mega_prep_kernel<<<(MP_TASKS + 255) / 256, 256, 0, stream>>>(
            feat, weight, loop_w, src, dst, ety, featb, wtb, cnt, payload);
        fused_agg_mfma_kernel<<<NT16, 256, 0, stream>>>(
            featb, wtb, h_bias, cnt, payload, out);
    } else {
        loop_init_kernel<<<(NN + 3) / 4, 256, 0, stream>>>(
            feat, loop_w, h_bias, out);
        fused_edge_kernel<<<dim3(2048), 256, 0, stream>>>(
            feat, src, dst, ety, weight, out);
    }
}

// Round 7
// 157.739 us; speedup vs baseline: 1.0512x; 1.0512x over previous
//
#include <hip/hip_runtime.h>

#define NN 50000
#define NPAD 50048           // featb rows (tail zeroed); NPAD-1 is the shared zero-row
#define NE 500000
#define DD 128
#define NT32 1563            // ceil(NN/32) 32-node tiles
#define ZROW (NPAD - 1)

// ALPHA = 0.5 → both sqrt(ALPHA) and sqrt(1-ALPHA) are sqrt(0.5).
__device__ __constant__ float SQ_A = 0.70710678118654752440f;

typedef __attribute__((ext_vector_type(8))) short short8;
typedef __attribute__((ext_vector_type(4))) float float4v;

// float → bf16 bits, round-to-nearest-even.
__device__ inline ushort f2bf(float f)
{
    uint u = __float_as_uint(f);
    u += 0x7fffu + ((u >> 16) & 1u);
    return (ushort)(u >> 16);
}
__device__ inline uint pk2(float a, float b)
{
    return (uint)f2bf(a) | ((uint)f2bf(b) << 16);
}
__device__ inline float bf_lo(uint d) { return __uint_as_float(d << 16); }
__device__ inline float bf_hi(uint d) { return __uint_as_float(d & 0xffff0000u); }

// ---------------------------------------------------------------------------
// Mega-prep: (a) edge placement into fixed-capacity per-(node,rel) buckets
// payload[n*64 + r*32 + idx] = src (ushort; Poisson(5)/bucket → P(>32)≈1e-11);
// (b) feat fp32 → featb bf16 [NPAD][128] (rows >= NN zeroed → ZROW is the
// dummy row for padded gather slots); (c) W/loop_w → wtb bf16, ×sqrt(.5),
// row-permuted for the packed epilogue. cnt[2*NPAD] pre-zeroed by memset.
// ---------------------------------------------------------------------------
#define MP_FEAT (NPAD * 16)          // 16 chunks of 8 elems per row
#define MP_WTB  (3 * 2048)
#define MP_TASKS (NE + MP_FEAT + MP_WTB)

__global__ __launch_bounds__(256)
void mega_prep_kernel(const float* __restrict__ feat,
                      const float* __restrict__ weight,
                      const float* __restrict__ loop_w,
                      const int* __restrict__ src,
                      const int* __restrict__ dst,
                      const int* __restrict__ ety,
                      ushort* __restrict__ featb,
                      ushort* __restrict__ wtb,
                      int* __restrict__ cnt,
                      ushort* __restrict__ payload)
{
    int t = blockIdx.x * 256 + threadIdx.x;
    if (t < NE) {
        // ---- edge placement (latency-heavy: schedule first) ----
        int d = dst[t], r = ety[t], s = src[t];
        int idx = atomicAdd(&cnt[2 * d + r], 1);
        if (idx < 32) payload[(d << 6) + (r << 5) + idx] = (ushort)s;
    } else if (t < NE + MP_FEAT) {
        int u   = t - NE;
        int row = u >> 4;
        int c   = u & 15;            // k-chunk: elems c*8 .. c*8+7
        float4 v0 = make_float4(0.f, 0.f, 0.f, 0.f), v1 = v0;
        if (row < NN) {
            const float4* p = (const float4*)(feat + (size_t)row * DD + c * 8);
            v0 = p[0]; v1 = p[1];
        }
        uint4 pk;
        pk.x = pk2(v0.x, v0.y); pk.y = pk2(v0.z, v0.w);
        pk.z = pk2(v1.x, v1.y); pk.w = pk2(v1.z, v1.w);
        *(uint4*)&featb[(size_t)row * DD + c * 8] = pk;
    } else if (t < MP_TASKS) {
        int u   = t - (NE + MP_FEAT);
        int seg = u >> 11;           // 0,1 → relations; 2 → loop
        int c   = (u >> 7) & 15;     // k-chunk
        int col = u & 127;           // actual output column
        const float* wsrc = (seg < 2) ? (weight + (size_t)seg * DD * DD)
                                      : loop_w;
        float v[8];
#pragma unroll
        for (int j = 0; j < 8; ++j)
            v[j] = wsrc[(size_t)(c * 8 + j) * DD + col] * SQ_A;
        uint4 pk;
        pk.x = pk2(v[0], v[1]); pk.y = pk2(v[2], v[3]);
        pk.z = pk2(v[4], v[5]); pk.w = pk2(v[6], v[7]);
        int prow = (col >> 5) * 32 + ((col & 1) << 4) + ((col & 31) >> 1);
        *(uint4*)&wtb[((size_t)seg * DD + prow) * DD + c * 8] = pk;
    }
}

// ---------------------------------------------------------------------------
// Overflow batch (deg_rel > 8; P ≈ 7% per bucket — off the hot path).
// ---------------------------------------------------------------------------
__device__ inline void ov8(const uint* __restrict__ fbu,
                           const ushort* __restrict__ pb,
                           int e, int c, int lane,
                           float2& sa, float2& sb)
{
    uint4 ch = *(const uint4*)(pb + e);
    uint w[4] = {ch.x, ch.y, ch.z, ch.w};
    uint d[8];
#pragma unroll
    for (int j = 0; j < 8; ++j) {
        int ps = __builtin_amdgcn_readfirstlane(
            (int)((w[j >> 1] >> ((j & 1) << 4)) & 0xffffu));
        ps = (e + j < c) ? ps : ZROW;
        d[j] = fbu[((size_t)ps << 6) + lane];
    }
#pragma unroll
    for (int j = 0; j < 8; j += 2) {
        sa.x += bf_lo(d[j]);     sa.y += bf_hi(d[j]);
        sb.x += bf_lo(d[j + 1]); sb.y += bf_hi(d[j + 1]);
    }
}

// ---------------------------------------------------------------------------
// Fused aggregate + transform. One block per 32-node tile, 4 waves; wave wv
// gathers nodes [wv*8, wv*8+8) (R1-proven gather: 17 loads per node in
// flight, slot padding via ZROW, 1-deep metadata prefetch). R2-R4 evidence:
// gather runs at the memory system's random-256B service rate; prefetch,
// wider loads, and occupancy changes are neutral-to-negative. So trim
// per-block overhead instead:
//   - sAgg holds ONLY the two relation planes (17.4 KB, was 26.1); the
//     self-loop A-fragment is read directly from featb in the last panel.
//   - launch_bounds(256,7): 7 blocks/CU by LDS (122 KB).
// NOTE (R5 bug, fixed): tile M = 32 rows → acc[2][2], mt<2 EVERYWHERE
// (phase-2 sAgg reads, self-panel featb rows, epilogue). mt<4 read sAgg
// out-of-bounds (NaN) and trampled the next block's output rows.
// ---------------------------------------------------------------------------
__global__ __launch_bounds__(256, 7)
void fused_agg_mfma_kernel(const ushort* __restrict__ featb,
                           const ushort* __restrict__ wtb,
                           const float* __restrict__ h_bias,
                           const int* __restrict__ cnt,
                           const ushort* __restrict__ payload,
                           float* __restrict__ out)
{
    __shared__ ushort sAgg[2][32][136];   // 17408 B → 7 blocks/CU

    const int node0 = blockIdx.x * 32;
    const int wv    = threadIdx.x >> 6;
    const int lane  = threadIdx.x & 63;
    const int mq    = lane & 15;
    const int quad  = lane >> 4;
    const int col0  = wv * 32;
    const uint* fbu = (const uint*)featb;

    // --- Phase 1: pipelined gather-aggregate, 8 nodes per wave. ---
    int  nnC = __builtin_amdgcn_readfirstlane(node0 + wv * 8);
    int2 ccC = *(const int2*)&cnt[2 * nnC];
    uint4 chA = *(const uint4*)(payload + ((size_t)nnC << 6));
    uint4 chB = *(const uint4*)(payload + ((size_t)nnC << 6) + 32);

#pragma unroll 1
    for (int i = 0; i < 8; ++i) {
        const int nl = wv * 8 + i;
        const int c0 = ccC.x < 32 ? ccC.x : 32;
        const int c1 = ccC.y < 32 ? ccC.y : 32;
        const uint wA[4] = {chA.x, chA.y, chA.z, chA.w};
        const uint wB[4] = {chB.x, chB.y, chB.z, chB.w};
        uint d[16];
#pragma unroll
        for (int j = 0; j < 8; ++j) {
            int ps = __builtin_amdgcn_readfirstlane(
                (int)((wA[j >> 1] >> ((j & 1) << 4)) & 0xffffu));
            ps = (j < c0) ? ps : ZROW;
            d[j] = fbu[((size_t)ps << 6) + lane];
        }
#pragma unroll
        for (int j = 0; j < 8; ++j) {
            int ps = __builtin_amdgcn_readfirstlane(
                (int)((wB[j >> 1] >> ((j & 1) << 4)) & 0xffffu));
            ps = (j < c1) ? ps : ZROW;
            d[8 + j] = fbu[((size_t)ps << 6) + lane];
        }
        // prefetch next node's metadata (in-bounds even at i==7: node0+32
        // ≤ 50016 < NPAD; cnt rows ≥ NN are zeroed → c==0 → unused)
        const int nnN = __builtin_amdgcn_readfirstlane(node0 + wv * 8 + i + 1);
        int2  ccN = *(const int2*)&cnt[2 * nnN];
        uint4 chAN = *(const uint4*)(payload + ((size_t)nnN << 6));
        uint4 chBN = *(const uint4*)(payload + ((size_t)nnN << 6) + 32);
        // accumulate current node (4 independent chains)
        float2 s0a = make_float2(0.f, 0.f), s0b = s0a, s1a = s0a, s1b = s0a;
#pragma unroll
        for (int j = 0; j < 8; j += 2) {
            s0a.x += bf_lo(d[j]);         s0a.y += bf_hi(d[j]);
            s0b.x += bf_lo(d[j + 1]);     s0b.y += bf_hi(d[j + 1]);
            s1a.x += bf_lo(d[8 + j]);     s1a.y += bf_hi(d[8 + j]);
            s1b.x += bf_lo(d[8 + j + 1]); s1b.y += bf_hi(d[8 + j + 1]);
        }
        if (c0 > 8)
            for (int e = 8; e < c0; e += 8)
                ov8(fbu, payload + ((size_t)nnC << 6), e, c0, lane, s0a, s0b);
        if (c1 > 8)
            for (int e = 8; e < c1; e += 8)
                ov8(fbu, payload + ((size_t)nnC << 6) + 32, e, c1, lane, s1a, s1b);
        *(uint*)&sAgg[0][nl][2 * lane] = pk2(s0a.x + s0b.x, s0a.y + s0b.y);
        *(uint*)&sAgg[1][nl][2 * lane] = pk2(s1a.x + s1b.x, s1a.y + s1b.y);
        nnC = nnN; ccC = ccN; chA = chAN; chB = chBN;
    }
    __syncthreads();

    // --- Phase 2: MFMA (M=32: mt<2). Panels 0,1 from sAgg (LDS);
    //     self-loop panel reads featb A-frags directly (global). ---
    float4v acc[2][2];
#pragma unroll
    for (int mt = 0; mt < 2; ++mt)
#pragma unroll
        for (int nt = 0; nt < 2; ++nt)
            acc[mt][nt] = (float4v){0.f, 0.f, 0.f, 0.f};

#pragma unroll 1
    for (int r = 0; r < 2; ++r) {
        const ushort* wseg = wtb + (size_t)r * DD * DD;
        short8 bfrag[2][4];
#pragma unroll
        for (int nt = 0; nt < 2; ++nt)
#pragma unroll
            for (int ks = 0; ks < 4; ++ks)
                bfrag[nt][ks] = *(const short8*)
                    &wseg[(size_t)(col0 + nt * 16 + mq) * DD + ks * 32 + quad * 8];
#pragma unroll
        for (int mt = 0; mt < 2; ++mt)
#pragma unroll
            for (int ks = 0; ks < 4; ++ks) {
                short8 a = *(const short8*)&sAgg[r][mt * 16 + mq][ks * 32 + quad * 8];
#pragma unroll
                for (int nt = 0; nt < 2; ++nt)
                    acc[mt][nt] = __builtin_amdgcn_mfma_f32_16x16x32_bf16(
                        a, bfrag[nt][ks], acc[mt][nt], 0, 0, 0);
            }
    }
    {
        const ushort* wseg = wtb + (size_t)2 * DD * DD;
        short8 bfrag[2][4];
#pragma unroll
        for (int nt = 0; nt < 2; ++nt)
#pragma unroll
            for (int ks = 0; ks < 4; ++ks)
                bfrag[nt][ks] = *(const short8*)
                    &wseg[(size_t)(col0 + nt * 16 + mq) * DD + ks * 32 + quad * 8];
#pragma unroll
        for (int mt = 0; mt < 2; ++mt) {
            const ushort* arow = featb + (size_t)(node0 + mt * 16 + mq) * DD;
#pragma unroll
            for (int ks = 0; ks < 4; ++ks) {
                short8 a = *(const short8*)&arow[ks * 32 + quad * 8];
#pragma unroll
                for (int nt = 0; nt < 2; ++nt)
                    acc[mt][nt] = __builtin_amdgcn_mfma_f32_16x16x32_bf16(
                        a, bfrag[nt][ks], acc[mt][nt], 0, 0, 0);
            }
        }
    }

    // Epilogue. D row = quad*4 + rr; lane mq owns cols col0+2mq, +1
    // (wtb row permutation makes nt=0/1 frags the even/odd columns).
    float2 bv = *(const float2*)&h_bias[col0 + 2 * mq];
#pragma unroll
    for (int mt = 0; mt < 2; ++mt) {
#pragma unroll
        for (int rr = 0; rr < 4; ++rr) {
            int node = node0 + mt * 16 + quad * 4 + rr;
            if (node < NN) {
                float2 v = make_float2(acc[mt][0][rr] + bv.x,
                                       acc[mt][1][rr] + bv.y);
                *(float2*)&out[(size_t)node * DD + col0 + 2 * mq] = v;
            }
        }
    }
}

// ---------------------------------------------------------------------------
// Fallback (small ws): fp32 out-init + fused per-edge matvec.
// ---------------------------------------------------------------------------
__global__ __launch_bounds__(256)
void loop_init_kernel(const float* __restrict__ feat,
                      const float* __restrict__ loop_weight,
                      const float* __restrict__ h_bias,
                      float* __restrict__ out)
{
    const int n = blockIdx.x * 4 + (threadIdx.x >> 6);
    if (n >= NN) return;
    const int lane = threadIdx.x & 63;
    const float2 fv = ((const float2*)(feat + (size_t)n * DD))[lane];
    float a0 = h_bias[lane], a1 = h_bias[lane + 64];
    for (int k = 0; k < 64; ++k) {
        float f0 = __shfl(fv.x, k, 64);
        float f1 = __shfl(fv.y, k, 64);
        a0 += SQ_A * (f0 * loop_weight[(size_t)(2 * k) * DD + lane]
                    + f1 * loop_weight[(size_t)(2 * k + 1) * DD + lane]);
        a1 += SQ_A * (f0 * loop_weight[(size_t)(2 * k) * DD + lane + 64]
                    + f1 * loop_weight[(size_t)(2 * k + 1) * DD + lane + 64]);
    }
    out[(size_t)n * DD + lane] = a0;
    out[(size_t)n * DD + lane + 64] = a1;
}

__global__ __launch_bounds__(256)
void fused_edge_kernel(const float* __restrict__ feat,
                       const int* __restrict__ src, const int* __restrict__ dst,
                       const int* __restrict__ ety,
                       const float* __restrict__ weight,
                       float* __restrict__ out)
{
    const int wave  = threadIdx.x >> 6;
    const int lane  = threadIdx.x & 63;
    const int nwav  = gridDim.x * 4;
    for (int e = blockIdx.x * 4 + wave; e < NE; e += nwav) {
        const int s = src[e];
        const int d = dst[e];
        const int r = ety[e];
        const float2 fv = ((const float2*)(feat + (size_t)s * DD))[lane];
        const float* W = weight + (size_t)r * DD * DD;
        float a0 = 0.f, a1 = 0.f;
        for (int k = 0; k < 64; ++k) {
            float f0 = __shfl(fv.x, k, 64);
            float f1 = __shfl(fv.y, k, 64);
            a0 += f0 * W[(size_t)(2 * k) * DD + lane]
                + f1 * W[(size_t)(2 * k + 1) * DD + lane];
            a1 += f0 * W[(size_t)(2 * k) * DD + lane + 64]
                + f1 * W[(size_t)(2 * k + 1) * DD + lane + 64];
        }
        atomicAdd(out + (size_t)d * DD + lane,      SQ_A * a0);
        atomicAdd(out + (size_t)d * DD + lane + 64, SQ_A * a1);
    }
}

extern "C" void kernel_launch(void* const* d_in, const int* in_sizes, int n_in,
                              void* d_out, int out_size, void* d_ws, size_t ws_size,
                              hipStream_t stream)
{
    const float* feat   = (const float*)d_in[0];
    const int*   src    = (const int*)d_in[1];
    const int*   dst    = (const int*)d_in[2];
    const int*   ety    = (const int*)d_in[3];
    const float* weight = (const float*)d_in[4];
    const float* loop_w = (const float*)d_in[5];
    const float* h_bias = (const float*)d_in[6];
    float* out  = (float*)d_out;

    // Workspace layout (all sections 16B-multiple sized). ~19.7 MiB total.
    char* p = (char*)d_ws;
    ushort* featb   = (ushort*)p; p += (size_t)NPAD * DD * 2;       // 12.81 MB
    ushort* wtb     = (ushort*)p; p += (size_t)3 * DD * DD * 2;     // 96 KB
    int*    cnt     = (int*)p;    p += (size_t)2 * NPAD * 4;        // 400 KB
    ushort* payload = (ushort*)p; p += (size_t)NPAD * 64 * 2;       // 6.4 MB
    const size_t need_full = (size_t)(p - (char*)d_ws);

    if (ws_size >= need_full) {
        hipMemsetAsync(cnt, 0, (size_t)2 * NPAD * 4, stream);
        mega_prep_kernel<<<(MP_TASKS + 255) / 256, 256, 0, stream>>>(
            feat, weight, loop_w, src, dst, ety, featb, wtb, cnt, payload);
        fused_agg_mfma_kernel<<<NT32, 256, 0, stream>>>(
            featb, wtb, h_bias, cnt, payload, out);
    } else {
        loop_init_kernel<<<(NN + 3) / 4, 256, 0, stream>>>(
            feat, loop_w, h_bias, out);
        fused_edge_kernel<<<dim3(2048), 256, 0, stream>>>(
            feat, src, dst, ety, weight, out);
    }
}